// Round 7
// baseline (1441.564 us; speedup 1.0000x reference)
//
#include <hip/hip_runtime.h>

#define KC    8192
#define DD    512
#define BNR   32768
#define NQ    4
#define QC    (KC/NQ)

typedef _Float16 half8 __attribute__((ext_vector_type(8)));
typedef float float4v __attribute__((ext_vector_type(4)));

// ---------------------------------------------------------------------------
// global -> LDS async DMA, 16B per lane (dest = wave-uniform base + lane*16)
// ---------------------------------------------------------------------------
typedef __attribute__((address_space(1))) const unsigned int gu32c;
typedef __attribute__((address_space(3))) unsigned int lu32;
__device__ __forceinline__ void gload_lds16(const _Float16* g, _Float16* l) {
    __builtin_amdgcn_global_load_lds((gu32c*)g, (lu32*)l, 16, 0, 0);
}

// ---------------------------------------------------------------------------
// sq helper (exact, no contraction)
// ---------------------------------------------------------------------------
__device__ __forceinline__ float sqf(const float* p, int i) {
    return __fmul_rn(p[i], p[i]);
}

// ---------------------------------------------------------------------------
// Wave-per-row np.sum(x*x, axis=1), bit-exact vs NumPy pairwise reduce:
// res = x0^2 + [(A+B)+(C+(D+E))], blocks A(1,120) B(121,128) C(249,128)
// D(377,64) E(441,71). Within a block: 8 accumulators r[j] (lane j of the
// 8-lane group), combine ((r0+r1)+(r2+r3))+((r4+r5)+(r6+r7)) via shfl_xor
// (commutative adds -> identical rounding), E remainder sequential.
// ---------------------------------------------------------------------------
__global__ __launch_bounds__(256) void rowsq_wave_kernel(const float* __restrict__ x,
                                                         float* __restrict__ out, int nrows) {
    const int wid = (int)((blockIdx.x * 256 + threadIdx.x) >> 6);
    if (wid >= nrows) return;                 // wave-uniform
    const int lane = threadIdx.x & 63;
    const float* p = x + (size_t)wid * DD;
    const int g = lane >> 3, j = lane & 7;
    const int offs[8] = {1, 121, 249, 377, 441, 0, 0, 0};
    const int its[8]  = {15, 16, 16, 8, 8, 0, 0, 0};
    float r = 0.0f;
    if (g < 5) {
        const int off = offs[g], n = its[g];
        r = sqf(p, off + j);
        for (int i = 1; i < n; i++) r = __fadd_rn(r, sqf(p, off + 8 * i + j));
    }
    r = __fadd_rn(r, __shfl_xor(r, 1, 64));
    r = __fadd_rn(r, __shfl_xor(r, 2, 64));
    r = __fadd_rn(r, __shfl_xor(r, 4, 64));
    float e = r;
    if (lane == 32) {                          // E remainder: x[505..511]
        for (int k = 0; k < 7; k++) e = __fadd_rn(e, sqf(p, 505 + k));
    }
    const float A = __shfl(r, 0, 64);
    const float B = __shfl(r, 8, 64);
    const float C = __shfl(r, 16, 64);
    const float Dv = __shfl(r, 24, 64);
    const float E = __shfl(e, 32, 64);
    if (lane == 0) {
        const float s511 = __fadd_rn(__fadd_rn(A, B), __fadd_rn(C, __fadd_rn(Dv, E)));
        out[wid] = __fadd_rn(sqf(p, 0), s511);
    }
}

// ---------------------------------------------------------------------------
// Splits. z: hi only (scale 2^11). e: hi+lo (scale 2^20). Kept products
// x_hi*e_hi and x_hi*e_lo share the 2^31 scale.
// ---------------------------------------------------------------------------
__global__ __launch_bounds__(256) void split_hi_kernel(const float* __restrict__ x,
        _Float16* __restrict__ xhi, float scale, int* __restrict__ counters) {
    if (counters && blockIdx.x == 0 && threadIdx.x == 0) { counters[0] = 0; counters[1] = 0; }
    const size_t i8 = ((size_t)blockIdx.x * 256 + threadIdx.x) * 8;
    const float4 v0 = *(const float4*)(x + i8);
    const float4 v1 = *(const float4*)(x + i8 + 4);
    const float s[8] = {v0.x, v0.y, v0.z, v0.w, v1.x, v1.y, v1.z, v1.w};
    half8 h;
#pragma unroll
    for (int j = 0; j < 8; j++) h[j] = (_Float16)(s[j] * scale);
    *(half8*)(xhi + i8) = h;
}

__global__ __launch_bounds__(256) void split_hilo_kernel(const float* __restrict__ x,
        _Float16* __restrict__ xhi, _Float16* __restrict__ xlo, float scale) {
    const size_t i8 = ((size_t)blockIdx.x * 256 + threadIdx.x) * 8;
    const float4 v0 = *(const float4*)(x + i8);
    const float4 v1 = *(const float4*)(x + i8 + 4);
    const float s[8] = {v0.x, v0.y, v0.z, v0.w, v1.x, v1.y, v1.z, v1.w};
    half8 h, l;
#pragma unroll
    for (int j = 0; j < 8; j++) {
        const float xs = s[j] * scale;
        const _Float16 hh = (_Float16)xs;
        h[j] = hh;
        l[j] = (_Float16)(xs - (float)hh);
    }
    *(half8*)(xhi + i8) = h;
    *(half8*)(xlo + i8) = l;
}

// ---------------------------------------------------------------------------
// top-3 merge (r4, validated)
// ---------------------------------------------------------------------------
__device__ __forceinline__ void merge3(float& d1, int& i1, float& d2, int& i2, float& d3,
                                       float od1, int oi1, float od2, int oi2, float od3) {
    const bool t1 = (od1 < d1) || (od1 == d1 && oi1 < i1);
    const float wd2 = t1 ? od2 : d2;  const int wi2 = t1 ? oi2 : i2;
    const float l1  = t1 ? d1  : od1; const int li1 = t1 ? i1  : oi1;
    const bool t2 = (l1 < wd2) || (l1 == wd2 && li1 < wi2);
    const float m1 = fmaxf(d1, od1);
    const float m2 = fminf(d2, od2);
    const float m3 = fminf(d3, od3);
    d3 = fmaxf(fminf(fmaxf(m1, m2), m3), fminf(m1, m2));
    d2 = t2 ? l1 : wd2;  i2 = t2 ? li1 : wi2;
    d1 = t1 ? od1 : d1;  i1 = t1 ? oi1 : i1;
}

// ---------------------------------------------------------------------------
// Main: 2-pass fp16 MFMA (x_hi*e_hi + x_hi*e_lo) + top-3.
// v7 = R3 geometry (128-row, 4 waves, 2 blocks/CU) with A moved to VGPRs:
//   - A fragments loaded global->reg, ping-pong sets, issued 1 iteration
//     ahead (A is L2-resident: 15/16 re-reads hit). A leaves LDS entirely.
//   - B (ehi+elo) DMA-staged into 3 x 16 KB LDS buffers, STAGE(it+2) at it.
//   - Per-wave vmem issue order (pinned by sched_barrier):
//       [wait vmcnt(8)][s_barrier][ALOAD A(it+1) x4][STAGE B(it+2) x4]
//     Steady-state FIFO at top of it = [B(it)4, A(it)4, B(it+1)4]:
//     vmcnt(8) drains exactly B(it); compiler's A(it)-use wait is already
//     satisfied (A issued a full iteration earlier). R2's failure was A
//     sitting OLDEST in the FIFO under the top wait — fixed by this order.
//   - ce[] hoisted right after the barrier on fold iterations so its
//     implicit use-wait doesn't drain the staging pipeline.
//   LDS per buffer (halves): Bh[0,4096) Bl[4096,8192); 16B chunk at
//   (row, slot p) holds global chunk q = p ^ ((row>>1)&3) (verified: 0
//   conflicts). Fragment values bit-identical to R3 (same bytes to MFMA).
// ---------------------------------------------------------------------------
#define LBUF 8192   // halves per B buffer (16 KB); 3 buffers = 48 KB

__global__ __launch_bounds__(256, 2) void mfma_argmin_kernel(
    const _Float16* __restrict__ xhi,
    const _Float16* __restrict__ ehi, const _Float16* __restrict__ elo,
    const float* __restrict__ ce,
    float* __restrict__ pd1, int* __restrict__ pi1,
    float* __restrict__ pd2, int* __restrict__ pi2, float* __restrict__ pd3) {

    __shared__ _Float16 lds[3 * LBUF];       // 48 KB

    const int tid  = threadIdx.x;
    const int tileR = blockIdx.x >> 2;
    const int q     = blockIdx.x & 3;
    const int r0    = tileR * 128;
    const int cq    = q * QC;

    const int lane = tid & 63;
    const int w    = tid >> 6;
    const int wr   = w >> 1, wc = w & 1;
    const int n16  = lane & 15, quad = lane >> 4;

    // B staging lane constants: lane l covers (subrow = l>>2, slot = l&3),
    // fetching global chunk q = (l&3) ^ ((l>>3)&3)
    const int sl_row = lane >> 2;
    const int sl_q   = (lane & 3) ^ ((lane >> 3) & 3);
    const size_t sl_goff = (size_t)sl_row * DD + (size_t)sl_q * 8;

    // B read-side swizzle: chunk slot = quad ^ ((n16>>1)&3), in halves
    const int rdo = (quad ^ ((n16 >> 1) & 3)) << 3;

    // A direct-load bases (per fm); per-iteration k offset added at load
    const _Float16* aP[4];
#pragma unroll
    for (int fm = 0; fm < 4; fm++)
        aP[fm] = xhi + (size_t)(r0 + wr * 64 + fm * 16 + n16) * DD + quad * 8;

    float bd1[16], bd2[16], bd3[16];
    int   bi1[16], bi2[16];
#pragma unroll
    for (int s = 0; s < 16; s++) {
        bd1[s] = 3.4e38f; bd2[s] = 3.4e38f; bd3[s] = 3.4e38f;
        bi1[s] = 0; bi2[s] = 0;
    }

    const float sc = -9.31322574615478515625e-10f;   // -2^-30

// stage one K-slice of Bh(128x32)+Bl(128x32) = 16 x 1KB DMA, 4 per wave
#define STAGEB(bidx_, nit_) do {                                                \
    const int kq_ = ((nit_) & 15) * 32;                                         \
    const size_t bb_ = (size_t)(cq + ((nit_) >> 4) * 128) * DD + kq_ + sl_goff; \
    _Float16* lb_ = lds + (bidx_) * LBUF;                                       \
    _Pragma("unroll")                                                           \
    for (int u_ = 0; u_ < 4; u_++) {                                            \
        const int j_ = w * 4 + u_;                                              \
        const int t_ = j_ >> 3;                                                 \
        const int s_ = j_ & 7;                                                  \
        const _Float16* g_ = (t_ == 0) ? (ehi + bb_ + (size_t)s_ * (16 * DD))   \
                                       : (elo + bb_ + (size_t)s_ * (16 * DD));  \
        gload_lds16(g_, lb_ + t_ * 4096 + s_ * 512);                            \
    }                                                                           \
} while (0)

#define ALOAD(dst_, nit_) do {                                                  \
    const int kq_ = ((nit_) & 15) * 32;                                         \
    _Pragma("unroll")                                                           \
    for (int fm_ = 0; fm_ < 4; fm_++)                                           \
        dst_[fm_] = *(const half8*)(aP[fm_] + kq_);                             \
} while (0)

// one iteration. Issue discipline (see header comment):
//   wait vmcnt(8); barrier; [ce on fold iters]; ALOAD A(it+1); STAGE B(it+2);
//   compute(A(it), B(it)); fold.
#define BODY(it_, Acur_, Anxt_) do {                                            \
    if ((it_) == 255) { asm volatile("s_waitcnt vmcnt(0)" ::: "memory"); }      \
    else              { asm volatile("s_waitcnt vmcnt(8)" ::: "memory"); }      \
    __builtin_amdgcn_s_barrier();                                               \
    __builtin_amdgcn_sched_barrier(0);                                          \
    float cek[4];                                                               \
    if (((it_) & 15) == 15) {                                                   \
        const int c0_ = cq + ((it_) >> 4) * 128;                                \
        _Pragma("unroll")                                                       \
        for (int fn_ = 0; fn_ < 4; fn_++)                                       \
            cek[fn_] = ce[c0_ + wc * 64 + fn_ * 16 + n16];                      \
    }                                                                           \
    if ((it_) < 255) ALOAD(Anxt_, (it_) + 1);                                   \
    __builtin_amdgcn_sched_barrier(0);                                          \
    if ((it_) < 254) STAGEB(bst, (it_) + 2);                                    \
    const _Float16* cb_ = lds + bcur * LBUF;                                    \
    _Pragma("unroll")                                                           \
    for (int fn = 0; fn < 4; fn++) {                                            \
        const int off = (wc * 64 + fn * 16 + n16) * 32 + rdo;                   \
        const half8 Bh = *(const half8*)(cb_ + off);                            \
        const half8 Bl = *(const half8*)(cb_ + 4096 + off);                     \
        _Pragma("unroll")                                                       \
        for (int fm = 0; fm < 4; fm++)                                          \
            acc[fm][fn] = __builtin_amdgcn_mfma_f32_16x16x32_f16(Acur_[fm], Bh, acc[fm][fn], 0, 0, 0); \
        _Pragma("unroll")                                                       \
        for (int fm = 0; fm < 4; fm++)                                          \
            acc[fm][fn] = __builtin_amdgcn_mfma_f32_16x16x32_f16(Acur_[fm], Bl, acc[fm][fn], 0, 0, 0); \
    }                                                                           \
    if (((it_) & 15) == 15) {                                                   \
        const int c0_ = cq + ((it_) >> 4) * 128;                                \
        _Pragma("unroll")                                                       \
        for (int fn = 0; fn < 4; fn++) {                                        \
            const int code = c0_ + wc * 64 + fn * 16 + n16;                     \
            _Pragma("unroll")                                                   \
            for (int fm = 0; fm < 4; fm++) {                                    \
                _Pragma("unroll")                                               \
                for (int reg = 0; reg < 4; reg++) {                             \
                    const int s = fm * 4 + reg;                                 \
                    const float d = fmaf(sc, acc[fm][fn][reg], cek[fn]);        \
                    const bool lt1 = d < bd1[s];                                \
                    const bool lt2 = d < bd2[s];                                \
                    const bool lt3 = d < bd3[s];                                \
                    bd3[s] = lt2 ? bd2[s] : (lt3 ? d : bd3[s]);                 \
                    bd2[s] = lt1 ? bd1[s] : (lt2 ? d : bd2[s]);                 \
                    bi2[s] = lt1 ? bi1[s] : (lt2 ? code : bi2[s]);              \
                    bd1[s] = lt1 ? d : bd1[s];                                  \
                    bi1[s] = lt1 ? code : bi1[s];                               \
                }                                                               \
            }                                                                   \
        }                                                                       \
        _Pragma("unroll")                                                       \
        for (int i_ = 0; i_ < 4; i_++)                                          \
            _Pragma("unroll")                                                   \
            for (int j2_ = 0; j2_ < 4; j2_++) acc[i_][j2_] = (float4v){0.f,0.f,0.f,0.f}; \
    }                                                                           \
    bcur = (bcur == 2) ? 0 : bcur + 1;                                          \
    bst  = (bst  == 2) ? 0 : bst  + 1;                                          \
} while (0)

    half8 Aa[4], Ab[4];
    // prologue: B0 -> buf0, B1 -> buf1, A0 -> regs
    // FIFO at top of it=0: [B(0)4, B(1)4, A(0)4]; vmcnt(8) drains B(0).
    STAGEB(0, 0);
    STAGEB(1, 1);
    ALOAD(Aa, 0);

    float4v acc[4][4];
#pragma unroll
    for (int i = 0; i < 4; i++)
#pragma unroll
        for (int jj = 0; jj < 4; jj++) acc[i][jj] = (float4v){0.f, 0.f, 0.f, 0.f};

    int bcur = 0, bst = 2;
    for (int it2 = 0; it2 < 256; it2 += 2) {
        BODY(it2,     Aa, Ab);
        BODY(it2 + 1, Ab, Aa);
    }

    // butterfly merge across 16 col-lanes
#pragma unroll
    for (int s = 0; s < 16; s++) {
#pragma unroll
        for (int off = 1; off < 16; off <<= 1) {
            const float od1 = __shfl_xor(bd1[s], off, 64);
            const int   oi1 = __shfl_xor(bi1[s], off, 64);
            const float od2 = __shfl_xor(bd2[s], off, 64);
            const int   oi2 = __shfl_xor(bi2[s], off, 64);
            const float od3 = __shfl_xor(bd3[s], off, 64);
            merge3(bd1[s], bi1[s], bd2[s], bi2[s], bd3[s], od1, oi1, od2, oi2, od3);
        }
    }

    __syncthreads();
    float* ld1 = (float*)lds;
    int*   li1 = (int*)(lds + 1024 * 1);
    float* ld2 = (float*)(lds + 1024 * 2);
    int*   li2 = (int*)(lds + 1024 * 3);
    float* ld3 = (float*)(lds + 1024 * 4);
    if (n16 == 0) {
#pragma unroll
        for (int fm = 0; fm < 4; fm++)
#pragma unroll
            for (int reg = 0; reg < 4; reg++) {
                const int s = fm * 4 + reg;
                const int rl = wr * 64 + fm * 16 + quad * 4 + reg;
                ld1[wc * 128 + rl] = bd1[s];
                li1[wc * 128 + rl] = bi1[s];
                ld2[wc * 128 + rl] = bd2[s];
                li2[wc * 128 + rl] = bi2[s];
                ld3[wc * 128 + rl] = bd3[s];
            }
    }
    __syncthreads();
    if (tid < 128) {
        float d1 = ld1[tid]; int i1 = li1[tid];
        float d2 = ld2[tid]; int i2 = li2[tid];
        float d3 = ld3[tid];
        merge3(d1, i1, d2, i2, d3,
               ld1[128 + tid], li1[128 + tid], ld2[128 + tid], li2[128 + tid], ld3[128 + tid]);
        const size_t o = (size_t)q * BNR + r0 + tid;
        pd1[o] = d1; pi1[o] = i1; pd2[o] = d2; pi2[o] = i2; pd3[o] = d3;
    }
}

// ---------------------------------------------------------------------------
// Combine + classify. band margin 2.5e-5 (covers 2x worst realistic eps of
// the 2-pass approximation; see round-5 analysis).
// ---------------------------------------------------------------------------
__global__ __launch_bounds__(256) void combine_kernel(
    const float* __restrict__ pd1, const int* __restrict__ pi1,
    const float* __restrict__ pd2, const int* __restrict__ pi2,
    const float* __restrict__ pd3,
    const float* __restrict__ a32, int* __restrict__ codes,
    int* __restrict__ pairlist, int* __restrict__ fulllist,
    unsigned long long* __restrict__ fkey, int* __restrict__ counters) {
    const int r = blockIdx.x * 256 + threadIdx.x;
    float d1 = pd1[r]; int i1 = pi1[r];
    float d2 = pd2[r]; int i2 = pi2[r];
    float d3 = pd3[r];
#pragma unroll
    for (int q = 1; q < NQ; q++) {
        const size_t o = (size_t)q * BNR + r;
        merge3(d1, i1, d2, i2, d3, pd1[o], pi1[o], pd2[o], pi2[o], pd3[o]);
    }
    codes[r] = i1;
    const float ap = a32[r] + 1.0f;
    const int ebits = (int)((__float_as_uint(ap) >> 23) & 255) - 127;
    const float ulpr = __uint_as_float((unsigned)(ebits - 23 + 127) << 23);
    const float band = 2.0f * ulpr + 2.5e-5f;
    if (d2 - d1 <= band) {
        if (d3 - d1 > band) {
            const int p = atomicAdd(&counters[0], 1);
            pairlist[2 * p]     = r;
            pairlist[2 * p + 1] = i1 | (i2 << 13);
        } else {
            const int p = atomicAdd(&counters[1], 1);
            fulllist[p] = r;
            fkey[p] = 0xFFFFFFFFFFFFFFFFULL;
        }
    }
}

// ---------------------------------------------------------------------------
// Pair repair (r4, validated): exact quantized compare of the two candidates.
// ---------------------------------------------------------------------------
__global__ __launch_bounds__(256) void pair_repair_kernel(
    const float* __restrict__ z, const float* __restrict__ embed,
    const float* __restrict__ ce, const float* __restrict__ a32,
    const int* __restrict__ pairlist, const int* __restrict__ counters,
    int* __restrict__ codes) {
    const int p = blockIdx.x * 4 + (threadIdx.x >> 6);
    if (p >= counters[0]) return;
    const int r  = pairlist[2 * p];
    const int pc = pairlist[2 * p + 1];
    const int c1 = pc & 8191, c2 = (pc >> 13) & 8191;
    const int lane = threadIdx.x & 63;
    const float* zr = z + (size_t)r * DD + lane * 8;
    const float* e1 = embed + (size_t)c1 * DD + lane * 8;
    const float* e2 = embed + (size_t)c2 * DD + lane * 8;
    const float4 x0 = *(const float4*)zr,        x1 = *(const float4*)(zr + 4);
    const float4 a0 = *(const float4*)e1,        a1 = *(const float4*)(e1 + 4);
    const float4 b0 = *(const float4*)e2,        b1 = *(const float4*)(e2 + 4);
    float s1 = x0.x*a0.x + x0.y*a0.y + x0.z*a0.z + x0.w*a0.w
             + x1.x*a1.x + x1.y*a1.y + x1.z*a1.z + x1.w*a1.w;
    float s2 = x0.x*b0.x + x0.y*b0.y + x0.z*b0.z + x0.w*b0.w
             + x1.x*b1.x + x1.y*b1.y + x1.z*b1.z + x1.w*b1.w;
#pragma unroll
    for (int off = 32; off > 0; off >>= 1) {
        s1 += __shfl_down(s1, off, 64);
        s2 += __shfl_down(s2, off, 64);
    }
    if (lane == 0) {
        const float ar = a32[r];
        const float dq1 = __fadd_rn(__fsub_rn(ar, __fmul_rn(2.0f, s1)), ce[c1]);
        const float dq2 = __fadd_rn(__fsub_rn(ar, __fmul_rn(2.0f, s2)), ce[c2]);
        const bool t = (dq2 < dq1) || (dq2 == dq1 && c2 < c1);
        codes[r] = t ? c2 : c1;
    }
}

// ---------------------------------------------------------------------------
// Full repair (r4, validated): row x code-chunk parallel, atomicMin u64 keys.
// ---------------------------------------------------------------------------
__global__ __launch_bounds__(256) void full_repair_kernel(
    const float* __restrict__ z, const float* __restrict__ embed,
    const float* __restrict__ ce, const float* __restrict__ a32,
    const int* __restrict__ fulllist, const int* __restrict__ counters,
    unsigned long long* __restrict__ fkey) {
    const int nf = counters[1];
    const int chunk = blockIdx.x & 7;
    const int lane = threadIdx.x & 63;
    const int wv = threadIdx.x >> 6;
    __shared__ float xs[512];
    for (int slot = blockIdx.x >> 3; slot < nf; slot += 2048) {
        const int r = fulllist[slot];
        __syncthreads();
        if (threadIdx.x < 128)
            ((float4*)xs)[threadIdx.x] = ((const float4*)(z + (size_t)r * DD))[threadIdx.x];
        __syncthreads();
        float x[8];
        *(float4*)&x[0] = ((float4*)xs)[lane * 2];
        *(float4*)&x[4] = ((float4*)xs)[lane * 2 + 1];
        const float ar = a32[r];
        float bd = 3.4e38f; int bc = 0x7fffffff;
        const int cbase = chunk * 1024 + wv * 256;
        for (int cc = 0; cc < 256; cc++) {
            const int c = cbase + cc;
            const float* er = embed + (size_t)c * DD + lane * 8;
            const float4 e0 = *(const float4*)er, e1 = *(const float4*)(er + 4);
            float s = x[0]*e0.x + x[1]*e0.y + x[2]*e0.z + x[3]*e0.w
                    + x[4]*e1.x + x[5]*e1.y + x[6]*e1.z + x[7]*e1.w;
#pragma unroll
            for (int off = 32; off > 0; off >>= 1) s += __shfl_down(s, off, 64);
            s = __shfl(s, 0, 64);
            const float dq = __fadd_rn(__fsub_rn(ar, __fmul_rn(2.0f, s)), ce[c]);
            if (dq < bd || (dq == bd && c < bc)) { bd = dq; bc = c; }
        }
        if (lane == 0) {
            unsigned int fb = __float_as_uint(bd);
            fb = (fb & 0x80000000u) ? ~fb : (fb | 0x80000000u);
            const unsigned long long key = ((unsigned long long)fb << 32) | (unsigned)bc;
            atomicMin(&fkey[slot], key);
        }
    }
}

__global__ __launch_bounds__(256) void full_combine_kernel(
    const unsigned long long* __restrict__ fkey, const int* __restrict__ fulllist,
    const int* __restrict__ counters, int* __restrict__ codes) {
    const int nf = counters[1];
    for (int p = blockIdx.x * 256 + threadIdx.x; p < nf; p += 32768)
        codes[fulllist[p]] = (int)(fkey[p] & 0xFFFFFFFFULL);
}

// ---------------------------------------------------------------------------
// Epilogue
// ---------------------------------------------------------------------------
__global__ __launch_bounds__(128) void gather_loss_kernel(
    const float* __restrict__ z, const float* __restrict__ embed,
    const int* __restrict__ codes,
    float* __restrict__ out_zq, float* __restrict__ out_codes,
    float* __restrict__ partial) {
    const int r = blockIdx.x;
    const int t = threadIdx.x;
    const int c = codes[r];
    const float4 zv = *(const float4*)(z + (size_t)r * DD + t * 4);
    const float4 ev = *(const float4*)(embed + (size_t)c * DD + t * 4);
    *(float4*)(out_zq + (size_t)r * DD + t * 4) = ev;
    const float dx = zv.x - ev.x, dy = zv.y - ev.y;
    const float dz2 = zv.z - ev.z, dw = zv.w - ev.w;
    float s = dx*dx + dy*dy + dz2*dz2 + dw*dw;
#pragma unroll
    for (int off = 32; off > 0; off >>= 1) s += __shfl_down(s, off, 64);
    __shared__ float wsum[2];
    if ((t & 63) == 0) wsum[t >> 6] = s;
    __syncthreads();
    if (t == 0) {
        partial[r] = wsum[0] + wsum[1];
        out_codes[r] = (float)c;
    }
}

__global__ __launch_bounds__(256) void loss_reduce_kernel(
    const float* __restrict__ partial, float* __restrict__ out_loss) {
    const int t = threadIdx.x;
    double s = 0.0;
    for (int i = t; i < BNR; i += 256) s += (double)partial[i];
    __shared__ double sd[256];
    sd[t] = s;
    __syncthreads();
    for (int k = 128; k > 0; k >>= 1) {
        if (t < k) sd[t] += sd[t + k];
        __syncthreads();
    }
    if (t == 0) out_loss[0] = (float)(0.1 * sd[0] / (double)((size_t)BNR * DD));
}

// ---------------------------------------------------------------------------
extern "C" void kernel_launch(void* const* d_in, const int* in_sizes, int n_in,
                              void* d_out, int out_size, void* d_ws, size_t ws_size,
                              hipStream_t stream) {
    const float* z     = (const float*)d_in[0];
    const float* embed = (const float*)d_in[1];
    float* out = (float*)d_out;
    float* out_zq    = out;
    float* out_codes = out + (size_t)BNR * DD;
    float* out_loss  = out + (size_t)BNR * DD + BNR;

    // z hi-split lives in the z_q output region (32 MB; overwritten at the end).
    _Float16* xhi = (_Float16*)d_out;

    char* ws = (char*)d_ws;
    int*   counters = (int*)  (ws + 0);
    float* ce       = (float*)(ws + 256);
    float* a32      = (float*)(ws + 33024);
    float* pd1      = (float*)(ws + 164096);
    int*   pi1      = (int*)  (ws + 688384);
    float* pd2      = (float*)(ws + 1212672);
    int*   pi2      = (int*)  (ws + 1736960);
    float* pd3      = (float*)(ws + 2261248);
    int*   codes    = (int*)  (ws + 2785536);
    int*   pairlist = (int*)  (ws + 2916608);
    int*   fulllist = (int*)  (ws + 3178752);
    unsigned long long* fkey = (unsigned long long*)(ws + 3309824);
    _Float16* ehi   = (_Float16*)(ws + 3571968);
    _Float16* elo   = (_Float16*)(ws + 11960576);
    float* partial  = pd1;                       // pd1 dead after combine

    split_hi_kernel<<<dim3(BNR * DD / 2048), dim3(256), 0, stream>>>(z, xhi, 2048.0f, counters);
    split_hilo_kernel<<<dim3(KC * DD / 2048), dim3(256), 0, stream>>>(embed, ehi, elo, 1048576.0f);
    rowsq_wave_kernel<<<dim3(BNR / 4), dim3(256), 0, stream>>>(z, a32, BNR);
    rowsq_wave_kernel<<<dim3(KC / 4), dim3(256), 0, stream>>>(embed, ce, KC);
    mfma_argmin_kernel<<<dim3((BNR / 128) * NQ), dim3(256), 0, stream>>>(
        xhi, ehi, elo, ce, pd1, pi1, pd2, pi2, pd3);
    combine_kernel<<<dim3(BNR / 256), dim3(256), 0, stream>>>(
        pd1, pi1, pd2, pi2, pd3, a32, codes, pairlist, fulllist, fkey, counters);
    pair_repair_kernel<<<dim3(8192), dim3(256), 0, stream>>>(
        z, embed, ce, a32, pairlist, counters, codes);
    full_repair_kernel<<<dim3(16384), dim3(256), 0, stream>>>(
        z, embed, ce, a32, fulllist, counters, fkey);
    full_combine_kernel<<<dim3(128), dim3(256), 0, stream>>>(
        fkey, fulllist, counters, codes);
    gather_loss_kernel<<<dim3(BNR), dim3(128), 0, stream>>>(
        z, embed, codes, out_zq, out_codes, partial);
    loss_reduce_kernel<<<dim3(1), dim3(256), 0, stream>>>(partial, out_loss);
}

// Round 8
// 1235.277 us; speedup vs baseline: 1.1670x; 1.1670x over previous
//
#include <hip/hip_runtime.h>

#define KC    8192
#define DD    512
#define BNR   32768
#define NQ    4
#define QC    (KC/NQ)

typedef _Float16 half8 __attribute__((ext_vector_type(8)));
typedef float float4v __attribute__((ext_vector_type(4)));

// ---------------------------------------------------------------------------
// global -> LDS async DMA, 16B per lane (dest = wave-uniform base + lane*16)
// ---------------------------------------------------------------------------
typedef __attribute__((address_space(1))) const unsigned int gu32c;
typedef __attribute__((address_space(3))) unsigned int lu32;
__device__ __forceinline__ void gload_lds16(const _Float16* g, _Float16* l) {
    __builtin_amdgcn_global_load_lds((gu32c*)g, (lu32*)l, 16, 0, 0);
}

// ---------------------------------------------------------------------------
// sq helper (exact, no contraction)
// ---------------------------------------------------------------------------
__device__ __forceinline__ float sqf(const float* p, int i) {
    return __fmul_rn(p[i], p[i]);
}

// ---------------------------------------------------------------------------
// Wave-per-row np.sum(x*x, axis=1), bit-exact vs NumPy pairwise reduce:
// res = x0^2 + [(A+B)+(C+(D+E))], blocks A(1,120) B(121,128) C(249,128)
// D(377,64) E(441,71). Within a block: 8 accumulators r[j] (lane j of the
// 8-lane group), combine ((r0+r1)+(r2+r3))+((r4+r5)+(r6+r7)) via shfl_xor
// (commutative adds -> identical rounding), E remainder sequential.
// ---------------------------------------------------------------------------
__global__ __launch_bounds__(256) void rowsq_wave_kernel(const float* __restrict__ x,
                                                         float* __restrict__ out, int nrows) {
    const int wid = (int)((blockIdx.x * 256 + threadIdx.x) >> 6);
    if (wid >= nrows) return;                 // wave-uniform
    const int lane = threadIdx.x & 63;
    const float* p = x + (size_t)wid * DD;
    const int g = lane >> 3, j = lane & 7;
    const int offs[8] = {1, 121, 249, 377, 441, 0, 0, 0};
    const int its[8]  = {15, 16, 16, 8, 8, 0, 0, 0};
    float r = 0.0f;
    if (g < 5) {
        const int off = offs[g], n = its[g];
        r = sqf(p, off + j);
        for (int i = 1; i < n; i++) r = __fadd_rn(r, sqf(p, off + 8 * i + j));
    }
    r = __fadd_rn(r, __shfl_xor(r, 1, 64));
    r = __fadd_rn(r, __shfl_xor(r, 2, 64));
    r = __fadd_rn(r, __shfl_xor(r, 4, 64));
    float e = r;
    if (lane == 32) {                          // E remainder: x[505..511]
        for (int k = 0; k < 7; k++) e = __fadd_rn(e, sqf(p, 505 + k));
    }
    const float A = __shfl(r, 0, 64);
    const float B = __shfl(r, 8, 64);
    const float C = __shfl(r, 16, 64);
    const float Dv = __shfl(r, 24, 64);
    const float E = __shfl(e, 32, 64);
    if (lane == 0) {
        const float s511 = __fadd_rn(__fadd_rn(A, B), __fadd_rn(C, __fadd_rn(Dv, E)));
        out[wid] = __fadd_rn(sqf(p, 0), s511);
    }
}

// ---------------------------------------------------------------------------
// Splits. z: hi only (scale 2^11). e: hi+lo (scale 2^20). Kept products
// x_hi*e_hi and x_hi*e_lo share the 2^31 scale.
// ---------------------------------------------------------------------------
__global__ __launch_bounds__(256) void split_hi_kernel(const float* __restrict__ x,
        _Float16* __restrict__ xhi, float scale, int* __restrict__ counters) {
    if (counters && blockIdx.x == 0 && threadIdx.x == 0) { counters[0] = 0; counters[1] = 0; }
    const size_t i8 = ((size_t)blockIdx.x * 256 + threadIdx.x) * 8;
    const float4 v0 = *(const float4*)(x + i8);
    const float4 v1 = *(const float4*)(x + i8 + 4);
    const float s[8] = {v0.x, v0.y, v0.z, v0.w, v1.x, v1.y, v1.z, v1.w};
    half8 h;
#pragma unroll
    for (int j = 0; j < 8; j++) h[j] = (_Float16)(s[j] * scale);
    *(half8*)(xhi + i8) = h;
}

__global__ __launch_bounds__(256) void split_hilo_kernel(const float* __restrict__ x,
        _Float16* __restrict__ xhi, _Float16* __restrict__ xlo, float scale) {
    const size_t i8 = ((size_t)blockIdx.x * 256 + threadIdx.x) * 8;
    const float4 v0 = *(const float4*)(x + i8);
    const float4 v1 = *(const float4*)(x + i8 + 4);
    const float s[8] = {v0.x, v0.y, v0.z, v0.w, v1.x, v1.y, v1.z, v1.w};
    half8 h, l;
#pragma unroll
    for (int j = 0; j < 8; j++) {
        const float xs = s[j] * scale;
        const _Float16 hh = (_Float16)xs;
        h[j] = hh;
        l[j] = (_Float16)(xs - (float)hh);
    }
    *(half8*)(xhi + i8) = h;
    *(half8*)(xlo + i8) = l;
}

// ---------------------------------------------------------------------------
// top-3 merge (r4, validated)
// ---------------------------------------------------------------------------
__device__ __forceinline__ void merge3(float& d1, int& i1, float& d2, int& i2, float& d3,
                                       float od1, int oi1, float od2, int oi2, float od3) {
    const bool t1 = (od1 < d1) || (od1 == d1 && oi1 < i1);
    const float wd2 = t1 ? od2 : d2;  const int wi2 = t1 ? oi2 : i2;
    const float l1  = t1 ? d1  : od1; const int li1 = t1 ? i1  : oi1;
    const bool t2 = (l1 < wd2) || (l1 == wd2 && li1 < wi2);
    const float m1 = fmaxf(d1, od1);
    const float m2 = fminf(d2, od2);
    const float m3 = fminf(d3, od3);
    d3 = fmaxf(fminf(fmaxf(m1, m2), m3), fminf(m1, m2));
    d2 = t2 ? l1 : wd2;  i2 = t2 ? li1 : wi2;
    d1 = t1 ? od1 : d1;  i1 = t1 ? oi1 : i1;
}

// ---------------------------------------------------------------------------
// Main: 2-pass fp16 MFMA (x_hi*e_hi + x_hi*e_lo) + top-3.
// v8 = R3 data path (all tiles DMA->LDS, XOR swizzle, 0 conflicts) with
//   compile-time addressing: 2 buffers (parity = slice&1) + 16x-unrolled
//   inner slice loop, so every LDS read/write offset is an instruction
//   immediate off thread-constant bases, and every DMA source is a fixed
//   base pointer + compile-time kq (folds into the 13-bit offset field).
//   B bases advance once per 128-code tile. Rationale: R3's VALUBusy 40.7%
//   was per-iteration address recompute (3-buffer runtime bases); the
//   kernel was issue-bound (MFMA 40% + VALU 40%). This removes the VALU.
//   Pipeline is 1-deep (stage slice it+1 after the barrier at it) -- the
//   R1-proven structure; the 3-buffer depth was only worth ~30us.
//   LDS per buffer (halves): A[0,4096) Bh[4096,8192) Bl[8192,12288).
//   16B chunk at (row, slot p) holds global chunk q = p ^ ((row>>1)&3).
//   Same MFMA operands and order as R3 -> bit-identical output.
// ---------------------------------------------------------------------------
#define LDSH 12288   // halves per buffer (24 KB); 2 buffers = 48 KB

__global__ __launch_bounds__(256, 2) void mfma_argmin_kernel(
    const _Float16* __restrict__ xhi,
    const _Float16* __restrict__ ehi, const _Float16* __restrict__ elo,
    const float* __restrict__ ce,
    float* __restrict__ pd1, int* __restrict__ pi1,
    float* __restrict__ pd2, int* __restrict__ pi2, float* __restrict__ pd3) {

    __shared__ _Float16 lds[2 * LDSH];       // 48 KB

    const int tid  = threadIdx.x;
    const int tileR = blockIdx.x >> 2;
    const int q     = blockIdx.x & 3;
    const int r0    = tileR * 128;
    const int cq    = q * QC;

    const int lane = tid & 63;
    const int w    = tid >> 6;
    const int wr   = w >> 1, wc = w & 1;
    const int n16  = lane & 15, quad = lane >> 4;

    // staging lane constants: lane l covers (subrow = l>>2, slot = l&3),
    // fetching global chunk q = (l&3) ^ ((l>>3)&3)
    const int sl_row = lane >> 2;
    const int sl_q   = (lane & 3) ^ ((lane >> 3) & 3);
    const size_t sl_goff = (size_t)sl_row * DD + (size_t)sl_q * 8;

    // read-side swizzle: chunk slot = quad ^ ((n16>>1)&3), in halves
    const int rdo = (quad ^ ((n16 >> 1) & 3)) << 3;

    // DMA descriptors (6 per wave): segment jj = w*6+u -> tile tt (0=A,1=Bh,
    // 2=Bl), 16-row segment ss. Source bases fixed (B advances per tile);
    // per-slice kq is a compile-time pointer offset at each unrolled site.
    const _Float16* dsrc[6];
    int ldso[6];
#pragma unroll
    for (int u = 0; u < 6; u++) {
        const int jj = w * 6 + u;
        const int tt = jj >> 3, ss = jj & 7;
        const _Float16* base = (tt == 0) ? (xhi + (size_t)r0 * DD)
                             : (tt == 1) ? (ehi + (size_t)cq * DD)
                                         : (elo + (size_t)cq * DD);
        dsrc[u] = base + (size_t)ss * (16 * DD) + sl_goff;
        ldso[u] = tt * 4096 + ss * 512;
    }

    // fragment read bases (halves within a buffer); fm/fn/region/buffer are
    // compile-time immediates at each unrolled site.
    const int aro = (wr * 64 + n16) * 32 + rdo;
    const int bro = (wc * 64 + n16) * 32 + rdo;

    float bd1[16], bd2[16], bd3[16];
    int   bi1[16], bi2[16];
#pragma unroll
    for (int s = 0; s < 16; s++) {
        bd1[s] = 3.4e38f; bd2[s] = 3.4e38f; bd3[s] = 3.4e38f;
        bi1[s] = 0; bi2[s] = 0;
    }

    const float sc = -9.31322574615478515625e-10f;   // -2^-30

    // prologue: slice 0 -> buffer 0
#pragma unroll
    for (int u = 0; u < 6; u++)
        gload_lds16(dsrc[u], lds + ldso[u]);

    float4v acc[4][4];
#pragma unroll
    for (int i = 0; i < 4; i++)
#pragma unroll
        for (int jj = 0; jj < 4; jj++) acc[i][jj] = (float4v){0.f, 0.f, 0.f, 0.f};

    for (int t = 0; t < 16; t++) {
#pragma unroll
        for (int j = 0; j < 16; j++) {
            // drains vmcnt(0): slice (t,j) DMA landed; all waves done reading
            // buffer (j+1)&1 (computed from at j-1) -> safe to overwrite.
            __syncthreads();

            if (!(t == 15 && j == 15)) {
                if (j == 15) {
                    // advance B sources to the next 128-code tile (A repeats)
#pragma unroll
                    for (int u = 0; u < 6; u++)
                        if (w * 6 + u >= 8) dsrc[u] += 128 * DD;
#pragma unroll
                    for (int u = 0; u < 6; u++)
                        gload_lds16(dsrc[u], lds + ldso[u]);          // buf 0
                } else {
#pragma unroll
                    for (int u = 0; u < 6; u++)
                        gload_lds16(dsrc[u] + (j + 1) * 32,
                                    lds + ldso[u] + ((j + 1) & 1) * LDSH);
                }
            }

            // compute slice (t,j) from buffer j&1 (all offsets immediate)
            const _Float16* cb = lds + (j & 1) * LDSH;
            half8 Ah[4];
#pragma unroll
            for (int fm = 0; fm < 4; fm++)
                Ah[fm] = *(const half8*)(cb + aro + fm * 512);
#pragma unroll
            for (int fn = 0; fn < 4; fn++) {
                const half8 Bh = *(const half8*)(cb + bro + 4096 + fn * 512);
                const half8 Bl = *(const half8*)(cb + bro + 8192 + fn * 512);
#pragma unroll
                for (int fm = 0; fm < 4; fm++)
                    acc[fm][fn] = __builtin_amdgcn_mfma_f32_16x16x32_f16(Ah[fm], Bh, acc[fm][fn], 0, 0, 0);
#pragma unroll
                for (int fm = 0; fm < 4; fm++)
                    acc[fm][fn] = __builtin_amdgcn_mfma_f32_16x16x32_f16(Ah[fm], Bl, acc[fm][fn], 0, 0, 0);
            }

            if (j == 15) {    // fold this 128-code tile
                const int c0 = cq + t * 128;
#pragma unroll
                for (int fn = 0; fn < 4; fn++) {
                    const int code = c0 + wc * 64 + fn * 16 + n16;
                    const float cek = ce[code];
#pragma unroll
                    for (int fm = 0; fm < 4; fm++) {
#pragma unroll
                        for (int reg = 0; reg < 4; reg++) {
                            const int s = fm * 4 + reg;
                            const float d = fmaf(sc, acc[fm][fn][reg], cek);
                            const bool lt1 = d < bd1[s];
                            const bool lt2 = d < bd2[s];
                            const bool lt3 = d < bd3[s];
                            bd3[s] = lt2 ? bd2[s] : (lt3 ? d : bd3[s]);
                            bd2[s] = lt1 ? bd1[s] : (lt2 ? d : bd2[s]);
                            bi2[s] = lt1 ? bi1[s] : (lt2 ? code : bi2[s]);
                            bd1[s] = lt1 ? d : bd1[s];
                            bi1[s] = lt1 ? code : bi1[s];
                        }
                    }
                }
#pragma unroll
                for (int i = 0; i < 4; i++)
#pragma unroll
                    for (int jj = 0; jj < 4; jj++) acc[i][jj] = (float4v){0.f, 0.f, 0.f, 0.f};
            }
        }
    }

    // butterfly merge across 16 col-lanes
#pragma unroll
    for (int s = 0; s < 16; s++) {
#pragma unroll
        for (int off = 1; off < 16; off <<= 1) {
            const float od1 = __shfl_xor(bd1[s], off, 64);
            const int   oi1 = __shfl_xor(bi1[s], off, 64);
            const float od2 = __shfl_xor(bd2[s], off, 64);
            const int   oi2 = __shfl_xor(bi2[s], off, 64);
            const float od3 = __shfl_xor(bd3[s], off, 64);
            merge3(bd1[s], bi1[s], bd2[s], bi2[s], bd3[s], od1, oi1, od2, oi2, od3);
        }
    }

    __syncthreads();
    float* ld1 = (float*)lds;
    int*   li1 = (int*)(lds + 1024 * 1);
    float* ld2 = (float*)(lds + 1024 * 2);
    int*   li2 = (int*)(lds + 1024 * 3);
    float* ld3 = (float*)(lds + 1024 * 4);
    if (n16 == 0) {
#pragma unroll
        for (int fm = 0; fm < 4; fm++)
#pragma unroll
            for (int reg = 0; reg < 4; reg++) {
                const int s = fm * 4 + reg;
                const int rl = wr * 64 + fm * 16 + quad * 4 + reg;
                ld1[wc * 128 + rl] = bd1[s];
                li1[wc * 128 + rl] = bi1[s];
                ld2[wc * 128 + rl] = bd2[s];
                li2[wc * 128 + rl] = bi2[s];
                ld3[wc * 128 + rl] = bd3[s];
            }
    }
    __syncthreads();
    if (tid < 128) {
        float d1 = ld1[tid]; int i1 = li1[tid];
        float d2 = ld2[tid]; int i2 = li2[tid];
        float d3 = ld3[tid];
        merge3(d1, i1, d2, i2, d3,
               ld1[128 + tid], li1[128 + tid], ld2[128 + tid], li2[128 + tid], ld3[128 + tid]);
        const size_t o = (size_t)q * BNR + r0 + tid;
        pd1[o] = d1; pi1[o] = i1; pd2[o] = d2; pi2[o] = i2; pd3[o] = d3;
    }
}

// ---------------------------------------------------------------------------
// Combine + classify. band margin 2.5e-5 (covers 2x worst realistic eps of
// the 2-pass approximation; see round-5 analysis).
// ---------------------------------------------------------------------------
__global__ __launch_bounds__(256) void combine_kernel(
    const float* __restrict__ pd1, const int* __restrict__ pi1,
    const float* __restrict__ pd2, const int* __restrict__ pi2,
    const float* __restrict__ pd3,
    const float* __restrict__ a32, int* __restrict__ codes,
    int* __restrict__ pairlist, int* __restrict__ fulllist,
    unsigned long long* __restrict__ fkey, int* __restrict__ counters) {
    const int r = blockIdx.x * 256 + threadIdx.x;
    float d1 = pd1[r]; int i1 = pi1[r];
    float d2 = pd2[r]; int i2 = pi2[r];
    float d3 = pd3[r];
#pragma unroll
    for (int q = 1; q < NQ; q++) {
        const size_t o = (size_t)q * BNR + r;
        merge3(d1, i1, d2, i2, d3, pd1[o], pi1[o], pd2[o], pi2[o], pd3[o]);
    }
    codes[r] = i1;
    const float ap = a32[r] + 1.0f;
    const int ebits = (int)((__float_as_uint(ap) >> 23) & 255) - 127;
    const float ulpr = __uint_as_float((unsigned)(ebits - 23 + 127) << 23);
    const float band = 2.0f * ulpr + 2.5e-5f;
    if (d2 - d1 <= band) {
        if (d3 - d1 > band) {
            const int p = atomicAdd(&counters[0], 1);
            pairlist[2 * p]     = r;
            pairlist[2 * p + 1] = i1 | (i2 << 13);
        } else {
            const int p = atomicAdd(&counters[1], 1);
            fulllist[p] = r;
            fkey[p] = 0xFFFFFFFFFFFFFFFFULL;
        }
    }
}

// ---------------------------------------------------------------------------
// Pair repair (r4, validated): exact quantized compare of the two candidates.
// ---------------------------------------------------------------------------
__global__ __launch_bounds__(256) void pair_repair_kernel(
    const float* __restrict__ z, const float* __restrict__ embed,
    const float* __restrict__ ce, const float* __restrict__ a32,
    const int* __restrict__ pairlist, const int* __restrict__ counters,
    int* __restrict__ codes) {
    const int p = blockIdx.x * 4 + (threadIdx.x >> 6);
    if (p >= counters[0]) return;
    const int r  = pairlist[2 * p];
    const int pc = pairlist[2 * p + 1];
    const int c1 = pc & 8191, c2 = (pc >> 13) & 8191;
    const int lane = threadIdx.x & 63;
    const float* zr = z + (size_t)r * DD + lane * 8;
    const float* e1 = embed + (size_t)c1 * DD + lane * 8;
    const float* e2 = embed + (size_t)c2 * DD + lane * 8;
    const float4 x0 = *(const float4*)zr,        x1 = *(const float4*)(zr + 4);
    const float4 a0 = *(const float4*)e1,        a1 = *(const float4*)(e1 + 4);
    const float4 b0 = *(const float4*)e2,        b1 = *(const float4*)(e2 + 4);
    float s1 = x0.x*a0.x + x0.y*a0.y + x0.z*a0.z + x0.w*a0.w
             + x1.x*a1.x + x1.y*a1.y + x1.z*a1.z + x1.w*a1.w;
    float s2 = x0.x*b0.x + x0.y*b0.y + x0.z*b0.z + x0.w*b0.w
             + x1.x*b1.x + x1.y*b1.y + x1.z*b1.z + x1.w*b1.w;
#pragma unroll
    for (int off = 32; off > 0; off >>= 1) {
        s1 += __shfl_down(s1, off, 64);
        s2 += __shfl_down(s2, off, 64);
    }
    if (lane == 0) {
        const float ar = a32[r];
        const float dq1 = __fadd_rn(__fsub_rn(ar, __fmul_rn(2.0f, s1)), ce[c1]);
        const float dq2 = __fadd_rn(__fsub_rn(ar, __fmul_rn(2.0f, s2)), ce[c2]);
        const bool t = (dq2 < dq1) || (dq2 == dq1 && c2 < c1);
        codes[r] = t ? c2 : c1;
    }
}

// ---------------------------------------------------------------------------
// Full repair (r4, validated): row x code-chunk parallel, atomicMin u64 keys.
// ---------------------------------------------------------------------------
__global__ __launch_bounds__(256) void full_repair_kernel(
    const float* __restrict__ z, const float* __restrict__ embed,
    const float* __restrict__ ce, const float* __restrict__ a32,
    const int* __restrict__ fulllist, const int* __restrict__ counters,
    unsigned long long* __restrict__ fkey) {
    const int nf = counters[1];
    const int chunk = blockIdx.x & 7;
    const int lane = threadIdx.x & 63;
    const int wv = threadIdx.x >> 6;
    __shared__ float xs[512];
    for (int slot = blockIdx.x >> 3; slot < nf; slot += 2048) {
        const int r = fulllist[slot];
        __syncthreads();
        if (threadIdx.x < 128)
            ((float4*)xs)[threadIdx.x] = ((const float4*)(z + (size_t)r * DD))[threadIdx.x];
        __syncthreads();
        float x[8];
        *(float4*)&x[0] = ((float4*)xs)[lane * 2];
        *(float4*)&x[4] = ((float4*)xs)[lane * 2 + 1];
        const float ar = a32[r];
        float bd = 3.4e38f; int bc = 0x7fffffff;
        const int cbase = chunk * 1024 + wv * 256;
        for (int cc = 0; cc < 256; cc++) {
            const int c = cbase + cc;
            const float* er = embed + (size_t)c * DD + lane * 8;
            const float4 e0 = *(const float4*)er, e1 = *(const float4*)(er + 4);
            float s = x[0]*e0.x + x[1]*e0.y + x[2]*e0.z + x[3]*e0.w
                    + x[4]*e1.x + x[5]*e1.y + x[6]*e1.z + x[7]*e1.w;
#pragma unroll
            for (int off = 32; off > 0; off >>= 1) s += __shfl_down(s, off, 64);
            s = __shfl(s, 0, 64);
            const float dq = __fadd_rn(__fsub_rn(ar, __fmul_rn(2.0f, s)), ce[c]);
            if (dq < bd || (dq == bd && c < bc)) { bd = dq; bc = c; }
        }
        if (lane == 0) {
            unsigned int fb = __float_as_uint(bd);
            fb = (fb & 0x80000000u) ? ~fb : (fb | 0x80000000u);
            const unsigned long long key = ((unsigned long long)fb << 32) | (unsigned)bc;
            atomicMin(&fkey[slot], key);
        }
    }
}

__global__ __launch_bounds__(256) void full_combine_kernel(
    const unsigned long long* __restrict__ fkey, const int* __restrict__ fulllist,
    const int* __restrict__ counters, int* __restrict__ codes) {
    const int nf = counters[1];
    for (int p = blockIdx.x * 256 + threadIdx.x; p < nf; p += 32768)
        codes[fulllist[p]] = (int)(fkey[p] & 0xFFFFFFFFULL);
}

// ---------------------------------------------------------------------------
// Epilogue
// ---------------------------------------------------------------------------
__global__ __launch_bounds__(128) void gather_loss_kernel(
    const float* __restrict__ z, const float* __restrict__ embed,
    const int* __restrict__ codes,
    float* __restrict__ out_zq, float* __restrict__ out_codes,
    float* __restrict__ partial) {
    const int r = blockIdx.x;
    const int t = threadIdx.x;
    const int c = codes[r];
    const float4 zv = *(const float4*)(z + (size_t)r * DD + t * 4);
    const float4 ev = *(const float4*)(embed + (size_t)c * DD + t * 4);
    *(float4*)(out_zq + (size_t)r * DD + t * 4) = ev;
    const float dx = zv.x - ev.x, dy = zv.y - ev.y;
    const float dz2 = zv.z - ev.z, dw = zv.w - ev.w;
    float s = dx*dx + dy*dy + dz2*dz2 + dw*dw;
#pragma unroll
    for (int off = 32; off > 0; off >>= 1) s += __shfl_down(s, off, 64);
    __shared__ float wsum[2];
    if ((t & 63) == 0) wsum[t >> 6] = s;
    __syncthreads();
    if (t == 0) {
        partial[r] = wsum[0] + wsum[1];
        out_codes[r] = (float)c;
    }
}

__global__ __launch_bounds__(256) void loss_reduce_kernel(
    const float* __restrict__ partial, float* __restrict__ out_loss) {
    const int t = threadIdx.x;
    double s = 0.0;
    for (int i = t; i < BNR; i += 256) s += (double)partial[i];
    __shared__ double sd[256];
    sd[t] = s;
    __syncthreads();
    for (int k = 128; k > 0; k >>= 1) {
        if (t < k) sd[t] += sd[t + k];
        __syncthreads();
    }
    if (t == 0) out_loss[0] = (float)(0.1 * sd[0] / (double)((size_t)BNR * DD));
}

// ---------------------------------------------------------------------------
extern "C" void kernel_launch(void* const* d_in, const int* in_sizes, int n_in,
                              void* d_out, int out_size, void* d_ws, size_t ws_size,
                              hipStream_t stream) {
    const float* z     = (const float*)d_in[0];
    const float* embed = (const float*)d_in[1];
    float* out = (float*)d_out;
    float* out_zq    = out;
    float* out_codes = out + (size_t)BNR * DD;
    float* out_loss  = out + (size_t)BNR * DD + BNR;

    // z hi-split lives in the z_q output region (32 MB; overwritten at the end).
    _Float16* xhi = (_Float16*)d_out;

    char* ws = (char*)d_ws;
    int*   counters = (int*)  (ws + 0);
    float* ce       = (float*)(ws + 256);
    float* a32      = (float*)(ws + 33024);
    float* pd1      = (float*)(ws + 164096);
    int*   pi1      = (int*)  (ws + 688384);
    float* pd2      = (float*)(ws + 1212672);
    int*   pi2      = (int*)  (ws + 1736960);
    float* pd3      = (float*)(ws + 2261248);
    int*   codes    = (int*)  (ws + 2785536);
    int*   pairlist = (int*)  (ws + 2916608);
    int*   fulllist = (int*)  (ws + 3178752);
    unsigned long long* fkey = (unsigned long long*)(ws + 3309824);
    _Float16* ehi   = (_Float16*)(ws + 3571968);
    _Float16* elo   = (_Float16*)(ws + 11960576);
    float* partial  = pd1;                       // pd1 dead after combine

    split_hi_kernel<<<dim3(BNR * DD / 2048), dim3(256), 0, stream>>>(z, xhi, 2048.0f, counters);
    split_hilo_kernel<<<dim3(KC * DD / 2048), dim3(256), 0, stream>>>(embed, ehi, elo, 1048576.0f);
    rowsq_wave_kernel<<<dim3(BNR / 4), dim3(256), 0, stream>>>(z, a32, BNR);
    rowsq_wave_kernel<<<dim3(KC / 4), dim3(256), 0, stream>>>(embed, ce, KC);
    mfma_argmin_kernel<<<dim3((BNR / 128) * NQ), dim3(256), 0, stream>>>(
        xhi, ehi, elo, ce, pd1, pi1, pd2, pi2, pd3);
    combine_kernel<<<dim3(BNR / 256), dim3(256), 0, stream>>>(
        pd1, pi1, pd2, pi2, pd3, a32, codes, pairlist, fulllist, fkey, counters);
    pair_repair_kernel<<<dim3(8192), dim3(256), 0, stream>>>(
        z, embed, ce, a32, pairlist, counters, codes);
    full_repair_kernel<<<dim3(16384), dim3(256), 0, stream>>>(
        z, embed, ce, a32, fulllist, counters, fkey);
    full_combine_kernel<<<dim3(128), dim3(256), 0, stream>>>(
        fkey, fulllist, counters, codes);
    gather_loss_kernel<<<dim3(BNR), dim3(128), 0, stream>>>(
        z, embed, codes, out_zq, out_codes, partial);
    loss_reduce_kernel<<<dim3(1), dim3(256), 0, stream>>>(partial, out_loss);
}

// Round 9
// 986.651 us; speedup vs baseline: 1.4611x; 1.2520x over previous
//
#include <hip/hip_runtime.h>

#define KC    8192
#define DD    512
#define BNR   32768
#define NQ    4
#define QC    (KC/NQ)

typedef _Float16 half8 __attribute__((ext_vector_type(8)));
typedef float float4v __attribute__((ext_vector_type(4)));

// ---------------------------------------------------------------------------
// global -> LDS async DMA, 16B per lane (dest = wave-uniform base + lane*16)
// ---------------------------------------------------------------------------
typedef __attribute__((address_space(1))) const unsigned int gu32c;
typedef __attribute__((address_space(3))) unsigned int lu32;
__device__ __forceinline__ void gload_lds16(const _Float16* g, _Float16* l) {
    __builtin_amdgcn_global_load_lds((gu32c*)g, (lu32*)l, 16, 0, 0);
}

// ---------------------------------------------------------------------------
// sq helper (exact, no contraction)
// ---------------------------------------------------------------------------
__device__ __forceinline__ float sqf(const float* p, int i) {
    return __fmul_rn(p[i], p[i]);
}

// ---------------------------------------------------------------------------
// Wave-per-row np.sum(x*x, axis=1), bit-exact vs NumPy pairwise reduce:
// res = x0^2 + [(A+B)+(C+(D+E))], blocks A(1,120) B(121,128) C(249,128)
// D(377,64) E(441,71). Within a block: 8 accumulators r[j] (lane j of the
// 8-lane group), combine ((r0+r1)+(r2+r3))+((r4+r5)+(r6+r7)) via shfl_xor
// (commutative adds -> identical rounding), E remainder sequential.
// ---------------------------------------------------------------------------
__global__ __launch_bounds__(256) void rowsq_wave_kernel(const float* __restrict__ x,
                                                         float* __restrict__ out, int nrows) {
    const int wid = (int)((blockIdx.x * 256 + threadIdx.x) >> 6);
    if (wid >= nrows) return;                 // wave-uniform
    const int lane = threadIdx.x & 63;
    const float* p = x + (size_t)wid * DD;
    const int g = lane >> 3, j = lane & 7;
    const int offs[8] = {1, 121, 249, 377, 441, 0, 0, 0};
    const int its[8]  = {15, 16, 16, 8, 8, 0, 0, 0};
    float r = 0.0f;
    if (g < 5) {
        const int off = offs[g], n = its[g];
        r = sqf(p, off + j);
        for (int i = 1; i < n; i++) r = __fadd_rn(r, sqf(p, off + 8 * i + j));
    }
    r = __fadd_rn(r, __shfl_xor(r, 1, 64));
    r = __fadd_rn(r, __shfl_xor(r, 2, 64));
    r = __fadd_rn(r, __shfl_xor(r, 4, 64));
    float e = r;
    if (lane == 32) {                          // E remainder: x[505..511]
        for (int k = 0; k < 7; k++) e = __fadd_rn(e, sqf(p, 505 + k));
    }
    const float A = __shfl(r, 0, 64);
    const float B = __shfl(r, 8, 64);
    const float C = __shfl(r, 16, 64);
    const float Dv = __shfl(r, 24, 64);
    const float E = __shfl(e, 32, 64);
    if (lane == 0) {
        const float s511 = __fadd_rn(__fadd_rn(A, B), __fadd_rn(C, __fadd_rn(Dv, E)));
        out[wid] = __fadd_rn(sqf(p, 0), s511);
    }
}

// ---------------------------------------------------------------------------
// Split. z: hi (scale 2^11). e: hi (scale 2^20). Kept product x_hi*e_hi has
// scale 2^31. v9 drops the e_lo pass: the dropped term 2*sum(x_hi*e_lo) has
// rms ~5e-7 (e_lo <= half-ulp of e*2^20 ~ 3e-8 unscaled, uncorrelated with
// x), comparable to the existing x-quant eps ~9e-7; the repair band margin
// is widened 2.5e-5 -> 3.0e-5 to keep >2x cushion over realized max eps.
// ---------------------------------------------------------------------------
__global__ __launch_bounds__(256) void split_hi_kernel(const float* __restrict__ x,
        _Float16* __restrict__ xhi, float scale, int* __restrict__ counters) {
    if (counters && blockIdx.x == 0 && threadIdx.x == 0) { counters[0] = 0; counters[1] = 0; }
    const size_t i8 = ((size_t)blockIdx.x * 256 + threadIdx.x) * 8;
    const float4 v0 = *(const float4*)(x + i8);
    const float4 v1 = *(const float4*)(x + i8 + 4);
    const float s[8] = {v0.x, v0.y, v0.z, v0.w, v1.x, v1.y, v1.z, v1.w};
    half8 h;
#pragma unroll
    for (int j = 0; j < 8; j++) h[j] = (_Float16)(s[j] * scale);
    *(half8*)(xhi + i8) = h;
}

// ---------------------------------------------------------------------------
// top-3 merge (r4, validated)
// ---------------------------------------------------------------------------
__device__ __forceinline__ void merge3(float& d1, int& i1, float& d2, int& i2, float& d3,
                                       float od1, int oi1, float od2, int oi2, float od3) {
    const bool t1 = (od1 < d1) || (od1 == d1 && oi1 < i1);
    const float wd2 = t1 ? od2 : d2;  const int wi2 = t1 ? oi2 : i2;
    const float l1  = t1 ? d1  : od1; const int li1 = t1 ? i1  : oi1;
    const bool t2 = (l1 < wd2) || (l1 == wd2 && li1 < wi2);
    const float m1 = fmaxf(d1, od1);
    const float m2 = fminf(d2, od2);
    const float m3 = fminf(d3, od3);
    d3 = fmaxf(fminf(fmaxf(m1, m2), m3), fminf(m1, m2));
    d2 = t2 ? l1 : wd2;  i2 = t2 ? li1 : wi2;
    d1 = t1 ? od1 : d1;  i1 = t1 ? oi1 : i1;
}

// ---------------------------------------------------------------------------
// Main: 1-pass fp16 MFMA (x_hi*e_hi) + top-3.
// v9 = v8 structure (compile-time addressing, 2 buffers, 16x-unrolled inner
//   slice loop, XOR swizzle, 0 conflicts) with the e_lo pass removed:
//   16 MFMAs/slice/wave (was 32), LDS reads 32 KB/block-slice (was 48),
//   DMA 16 KB (was 24), buffers 16 KB each (32 KB total).
//   LDS per buffer (halves): A[0,4096) Bh[4096,8192).
//   16B chunk at (row, slot p) holds global chunk q = p ^ ((row>>1)&3).
// ---------------------------------------------------------------------------
#define LDSH 8192    // halves per buffer (16 KB); 2 buffers = 32 KB

__global__ __launch_bounds__(256, 2) void mfma_argmin_kernel(
    const _Float16* __restrict__ xhi, const _Float16* __restrict__ ehi,
    const float* __restrict__ ce,
    float* __restrict__ pd1, int* __restrict__ pi1,
    float* __restrict__ pd2, int* __restrict__ pi2, float* __restrict__ pd3) {

    __shared__ _Float16 lds[2 * LDSH];       // 32 KB

    const int tid  = threadIdx.x;
    const int tileR = blockIdx.x >> 2;
    const int q     = blockIdx.x & 3;
    const int r0    = tileR * 128;
    const int cq    = q * QC;

    const int lane = tid & 63;
    const int w    = tid >> 6;
    const int wr   = w >> 1, wc = w & 1;
    const int n16  = lane & 15, quad = lane >> 4;

    // staging lane constants: lane l covers (subrow = l>>2, slot = l&3),
    // fetching global chunk q = (l&3) ^ ((l>>3)&3)
    const int sl_row = lane >> 2;
    const int sl_q   = (lane & 3) ^ ((lane >> 3) & 3);
    const size_t sl_goff = (size_t)sl_row * DD + (size_t)sl_q * 8;

    // read-side swizzle: chunk slot = quad ^ ((n16>>1)&3), in halves
    const int rdo = (quad ^ ((n16 >> 1) & 3)) << 3;

    // DMA descriptors (4 per wave): segment jj = w*4+u -> tile tt (0=A,1=Bh),
    // 16-row segment ss. Bases fixed (B advances once per 128-code tile);
    // per-slice kq is a compile-time pointer offset at each unrolled site.
    const _Float16* dsrc[4];
    int ldso[4];
#pragma unroll
    for (int u = 0; u < 4; u++) {
        const int jj = w * 4 + u;
        const int tt = jj >> 3, ss = jj & 7;
        const _Float16* base = (tt == 0) ? (xhi + (size_t)r0 * DD)
                                         : (ehi + (size_t)cq * DD);
        dsrc[u] = base + (size_t)ss * (16 * DD) + sl_goff;
        ldso[u] = tt * 4096 + ss * 512;
    }

    // fragment read bases (halves within a buffer)
    const int aro = (wr * 64 + n16) * 32 + rdo;
    const int bro = (wc * 64 + n16) * 32 + rdo;

    float bd1[16], bd2[16], bd3[16];
    int   bi1[16], bi2[16];
#pragma unroll
    for (int s = 0; s < 16; s++) {
        bd1[s] = 3.4e38f; bd2[s] = 3.4e38f; bd3[s] = 3.4e38f;
        bi1[s] = 0; bi2[s] = 0;
    }

    const float sc = -9.31322574615478515625e-10f;   // -2^-30

    // prologue: slice 0 -> buffer 0
#pragma unroll
    for (int u = 0; u < 4; u++)
        gload_lds16(dsrc[u], lds + ldso[u]);

    float4v acc[4][4];
#pragma unroll
    for (int i = 0; i < 4; i++)
#pragma unroll
        for (int jj = 0; jj < 4; jj++) acc[i][jj] = (float4v){0.f, 0.f, 0.f, 0.f};

    for (int t = 0; t < 16; t++) {
#pragma unroll
        for (int j = 0; j < 16; j++) {
            // drains vmcnt(0): slice (t,j) DMA landed; all waves done reading
            // buffer (j+1)&1 (computed from at j-1) -> safe to overwrite.
            __syncthreads();

            if (!(t == 15 && j == 15)) {
                if (j == 15) {
                    // advance B sources to the next 128-code tile (A repeats)
#pragma unroll
                    for (int u = 0; u < 4; u++)
                        if (w * 4 + u >= 8) dsrc[u] += 128 * DD;
#pragma unroll
                    for (int u = 0; u < 4; u++)
                        gload_lds16(dsrc[u], lds + ldso[u]);          // buf 0
                } else {
#pragma unroll
                    for (int u = 0; u < 4; u++)
                        gload_lds16(dsrc[u] + (j + 1) * 32,
                                    lds + ldso[u] + ((j + 1) & 1) * LDSH);
                }
            }

            // compute slice (t,j) from buffer j&1 (all offsets immediate)
            const _Float16* cb = lds + (j & 1) * LDSH;
            half8 Ah[4];
#pragma unroll
            for (int fm = 0; fm < 4; fm++)
                Ah[fm] = *(const half8*)(cb + aro + fm * 512);
#pragma unroll
            for (int fn = 0; fn < 4; fn++) {
                const half8 Bh = *(const half8*)(cb + bro + 4096 + fn * 512);
#pragma unroll
                for (int fm = 0; fm < 4; fm++)
                    acc[fm][fn] = __builtin_amdgcn_mfma_f32_16x16x32_f16(Ah[fm], Bh, acc[fm][fn], 0, 0, 0);
            }

            if (j == 15) {    // fold this 128-code tile
                const int c0 = cq + t * 128;
#pragma unroll
                for (int fn = 0; fn < 4; fn++) {
                    const int code = c0 + wc * 64 + fn * 16 + n16;
                    const float cek = ce[code];
#pragma unroll
                    for (int fm = 0; fm < 4; fm++) {
#pragma unroll
                        for (int reg = 0; reg < 4; reg++) {
                            const int s = fm * 4 + reg;
                            const float d = fmaf(sc, acc[fm][fn][reg], cek);
                            const bool lt1 = d < bd1[s];
                            const bool lt2 = d < bd2[s];
                            const bool lt3 = d < bd3[s];
                            bd3[s] = lt2 ? bd2[s] : (lt3 ? d : bd3[s]);
                            bd2[s] = lt1 ? bd1[s] : (lt2 ? d : bd2[s]);
                            bi2[s] = lt1 ? bi1[s] : (lt2 ? code : bi2[s]);
                            bd1[s] = lt1 ? d : bd1[s];
                            bi1[s] = lt1 ? code : bi1[s];
                        }
                    }
                }
#pragma unroll
                for (int i = 0; i < 4; i++)
#pragma unroll
                    for (int jj = 0; jj < 4; jj++) acc[i][jj] = (float4v){0.f, 0.f, 0.f, 0.f};
            }
        }
    }

    // butterfly merge across 16 col-lanes
#pragma unroll
    for (int s = 0; s < 16; s++) {
#pragma unroll
        for (int off = 1; off < 16; off <<= 1) {
            const float od1 = __shfl_xor(bd1[s], off, 64);
            const int   oi1 = __shfl_xor(bi1[s], off, 64);
            const float od2 = __shfl_xor(bd2[s], off, 64);
            const int   oi2 = __shfl_xor(bi2[s], off, 64);
            const float od3 = __shfl_xor(bd3[s], off, 64);
            merge3(bd1[s], bi1[s], bd2[s], bi2[s], bd3[s], od1, oi1, od2, oi2, od3);
        }
    }

    __syncthreads();
    float* ld1 = (float*)lds;
    int*   li1 = (int*)(lds + 1024 * 1);
    float* ld2 = (float*)(lds + 1024 * 2);
    int*   li2 = (int*)(lds + 1024 * 3);
    float* ld3 = (float*)(lds + 1024 * 4);
    if (n16 == 0) {
#pragma unroll
        for (int fm = 0; fm < 4; fm++)
#pragma unroll
            for (int reg = 0; reg < 4; reg++) {
                const int s = fm * 4 + reg;
                const int rl = wr * 64 + fm * 16 + quad * 4 + reg;
                ld1[wc * 128 + rl] = bd1[s];
                li1[wc * 128 + rl] = bi1[s];
                ld2[wc * 128 + rl] = bd2[s];
                li2[wc * 128 + rl] = bi2[s];
                ld3[wc * 128 + rl] = bd3[s];
            }
    }
    __syncthreads();
    if (tid < 128) {
        float d1 = ld1[tid]; int i1 = li1[tid];
        float d2 = ld2[tid]; int i2 = li2[tid];
        float d3 = ld3[tid];
        merge3(d1, i1, d2, i2, d3,
               ld1[128 + tid], li1[128 + tid], ld2[128 + tid], li2[128 + tid], ld3[128 + tid]);
        const size_t o = (size_t)q * BNR + r0 + tid;
        pd1[o] = d1; pi1[o] = i1; pd2[o] = d2; pi2[o] = i2; pd3[o] = d3;
    }
}

// ---------------------------------------------------------------------------
// Combine + classify. band margin 3.0e-5 (1-pass scheme: covers ~2x worst
// realistic eps incl. the dropped e_lo term; see round-8 analysis).
// ---------------------------------------------------------------------------
__global__ __launch_bounds__(256) void combine_kernel(
    const float* __restrict__ pd1, const int* __restrict__ pi1,
    const float* __restrict__ pd2, const int* __restrict__ pi2,
    const float* __restrict__ pd3,
    const float* __restrict__ a32, int* __restrict__ codes,
    int* __restrict__ pairlist, int* __restrict__ fulllist,
    unsigned long long* __restrict__ fkey, int* __restrict__ counters) {
    const int r = blockIdx.x * 256 + threadIdx.x;
    float d1 = pd1[r]; int i1 = pi1[r];
    float d2 = pd2[r]; int i2 = pi2[r];
    float d3 = pd3[r];
#pragma unroll
    for (int q = 1; q < NQ; q++) {
        const size_t o = (size_t)q * BNR + r;
        merge3(d1, i1, d2, i2, d3, pd1[o], pi1[o], pd2[o], pi2[o], pd3[o]);
    }
    codes[r] = i1;
    const float ap = a32[r] + 1.0f;
    const int ebits = (int)((__float_as_uint(ap) >> 23) & 255) - 127;
    const float ulpr = __uint_as_float((unsigned)(ebits - 23 + 127) << 23);
    const float band = 2.0f * ulpr + 3.0e-5f;
    if (d2 - d1 <= band) {
        if (d3 - d1 > band) {
            const int p = atomicAdd(&counters[0], 1);
            pairlist[2 * p]     = r;
            pairlist[2 * p + 1] = i1 | (i2 << 13);
        } else {
            const int p = atomicAdd(&counters[1], 1);
            fulllist[p] = r;
            fkey[p] = 0xFFFFFFFFFFFFFFFFULL;
        }
    }
}

// ---------------------------------------------------------------------------
// Pair repair (r4, validated): exact quantized compare of the two candidates.
// ---------------------------------------------------------------------------
__global__ __launch_bounds__(256) void pair_repair_kernel(
    const float* __restrict__ z, const float* __restrict__ embed,
    const float* __restrict__ ce, const float* __restrict__ a32,
    const int* __restrict__ pairlist, const int* __restrict__ counters,
    int* __restrict__ codes) {
    const int p = blockIdx.x * 4 + (threadIdx.x >> 6);
    if (p >= counters[0]) return;
    const int r  = pairlist[2 * p];
    const int pc = pairlist[2 * p + 1];
    const int c1 = pc & 8191, c2 = (pc >> 13) & 8191;
    const int lane = threadIdx.x & 63;
    const float* zr = z + (size_t)r * DD + lane * 8;
    const float* e1 = embed + (size_t)c1 * DD + lane * 8;
    const float* e2 = embed + (size_t)c2 * DD + lane * 8;
    const float4 x0 = *(const float4*)zr,        x1 = *(const float4*)(zr + 4);
    const float4 a0 = *(const float4*)e1,        a1 = *(const float4*)(e1 + 4);
    const float4 b0 = *(const float4*)e2,        b1 = *(const float4*)(e2 + 4);
    float s1 = x0.x*a0.x + x0.y*a0.y + x0.z*a0.z + x0.w*a0.w
             + x1.x*a1.x + x1.y*a1.y + x1.z*a1.z + x1.w*a1.w;
    float s2 = x0.x*b0.x + x0.y*b0.y + x0.z*b0.z + x0.w*b0.w
             + x1.x*b1.x + x1.y*b1.y + x1.z*b1.z + x1.w*b1.w;
#pragma unroll
    for (int off = 32; off > 0; off >>= 1) {
        s1 += __shfl_down(s1, off, 64);
        s2 += __shfl_down(s2, off, 64);
    }
    if (lane == 0) {
        const float ar = a32[r];
        const float dq1 = __fadd_rn(__fsub_rn(ar, __fmul_rn(2.0f, s1)), ce[c1]);
        const float dq2 = __fadd_rn(__fsub_rn(ar, __fmul_rn(2.0f, s2)), ce[c2]);
        const bool t = (dq2 < dq1) || (dq2 == dq1 && c2 < c1);
        codes[r] = t ? c2 : c1;
    }
}

// ---------------------------------------------------------------------------
// Full repair (r4, validated): row x code-chunk parallel, atomicMin u64 keys.
// ---------------------------------------------------------------------------
__global__ __launch_bounds__(256) void full_repair_kernel(
    const float* __restrict__ z, const float* __restrict__ embed,
    const float* __restrict__ ce, const float* __restrict__ a32,
    const int* __restrict__ fulllist, const int* __restrict__ counters,
    unsigned long long* __restrict__ fkey) {
    const int nf = counters[1];
    const int chunk = blockIdx.x & 7;
    const int lane = threadIdx.x & 63;
    const int wv = threadIdx.x >> 6;
    __shared__ float xs[512];
    for (int slot = blockIdx.x >> 3; slot < nf; slot += 2048) {
        const int r = fulllist[slot];
        __syncthreads();
        if (threadIdx.x < 128)
            ((float4*)xs)[threadIdx.x] = ((const float4*)(z + (size_t)r * DD))[threadIdx.x];
        __syncthreads();
        float x[8];
        *(float4*)&x[0] = ((float4*)xs)[lane * 2];
        *(float4*)&x[4] = ((float4*)xs)[lane * 2 + 1];
        const float ar = a32[r];
        float bd = 3.4e38f; int bc = 0x7fffffff;
        const int cbase = chunk * 1024 + wv * 256;
        for (int cc = 0; cc < 256; cc++) {
            const int c = cbase + cc;
            const float* er = embed + (size_t)c * DD + lane * 8;
            const float4 e0 = *(const float4*)er, e1 = *(const float4*)(er + 4);
            float s = x[0]*e0.x + x[1]*e0.y + x[2]*e0.z + x[3]*e0.w
                    + x[4]*e1.x + x[5]*e1.y + x[6]*e1.z + x[7]*e1.w;
#pragma unroll
            for (int off = 32; off > 0; off >>= 1) s += __shfl_down(s, off, 64);
            s = __shfl(s, 0, 64);
            const float dq = __fadd_rn(__fsub_rn(ar, __fmul_rn(2.0f, s)), ce[c]);
            if (dq < bd || (dq == bd && c < bc)) { bd = dq; bc = c; }
        }
        if (lane == 0) {
            unsigned int fb = __float_as_uint(bd);
            fb = (fb & 0x80000000u) ? ~fb : (fb | 0x80000000u);
            const unsigned long long key = ((unsigned long long)fb << 32) | (unsigned)bc;
            atomicMin(&fkey[slot], key);
        }
    }
}

__global__ __launch_bounds__(256) void full_combine_kernel(
    const unsigned long long* __restrict__ fkey, const int* __restrict__ fulllist,
    const int* __restrict__ counters, int* __restrict__ codes) {
    const int nf = counters[1];
    for (int p = blockIdx.x * 256 + threadIdx.x; p < nf; p += 32768)
        codes[fulllist[p]] = (int)(fkey[p] & 0xFFFFFFFFULL);
}

// ---------------------------------------------------------------------------
// Epilogue
// ---------------------------------------------------------------------------
__global__ __launch_bounds__(128) void gather_loss_kernel(
    const float* __restrict__ z, const float* __restrict__ embed,
    const int* __restrict__ codes,
    float* __restrict__ out_zq, float* __restrict__ out_codes,
    float* __restrict__ partial) {
    const int r = blockIdx.x;
    const int t = threadIdx.x;
    const int c = codes[r];
    const float4 zv = *(const float4*)(z + (size_t)r * DD + t * 4);
    const float4 ev = *(const float4*)(embed + (size_t)c * DD + t * 4);
    *(float4*)(out_zq + (size_t)r * DD + t * 4) = ev;
    const float dx = zv.x - ev.x, dy = zv.y - ev.y;
    const float dz2 = zv.z - ev.z, dw = zv.w - ev.w;
    float s = dx*dx + dy*dy + dz2*dz2 + dw*dw;
#pragma unroll
    for (int off = 32; off > 0; off >>= 1) s += __shfl_down(s, off, 64);
    __shared__ float wsum[2];
    if ((t & 63) == 0) wsum[t >> 6] = s;
    __syncthreads();
    if (t == 0) {
        partial[r] = wsum[0] + wsum[1];
        out_codes[r] = (float)c;
    }
}

__global__ __launch_bounds__(256) void loss_reduce_kernel(
    const float* __restrict__ partial, float* __restrict__ out_loss) {
    const int t = threadIdx.x;
    double s = 0.0;
    for (int i = t; i < BNR; i += 256) s += (double)partial[i];
    __shared__ double sd[256];
    sd[t] = s;
    __syncthreads();
    for (int k = 128; k > 0; k >>= 1) {
        if (t < k) sd[t] += sd[t + k];
        __syncthreads();
    }
    if (t == 0) out_loss[0] = (float)(0.1 * sd[0] / (double)((size_t)BNR * DD));
}

// ---------------------------------------------------------------------------
extern "C" void kernel_launch(void* const* d_in, const int* in_sizes, int n_in,
                              void* d_out, int out_size, void* d_ws, size_t ws_size,
                              hipStream_t stream) {
    const float* z     = (const float*)d_in[0];
    const float* embed = (const float*)d_in[1];
    float* out = (float*)d_out;
    float* out_zq    = out;
    float* out_codes = out + (size_t)BNR * DD;
    float* out_loss  = out + (size_t)BNR * DD + BNR;

    // z hi-split lives in the z_q output region (32 MB; overwritten at the end).
    _Float16* xhi = (_Float16*)d_out;

    char* ws = (char*)d_ws;
    int*   counters = (int*)  (ws + 0);
    float* ce       = (float*)(ws + 256);
    float* a32      = (float*)(ws + 33024);
    float* pd1      = (float*)(ws + 164096);
    int*   pi1      = (int*)  (ws + 688384);
    float* pd2      = (float*)(ws + 1212672);
    int*   pi2      = (int*)  (ws + 1736960);
    float* pd3      = (float*)(ws + 2261248);
    int*   codes    = (int*)  (ws + 2785536);
    int*   pairlist = (int*)  (ws + 2916608);
    int*   fulllist = (int*)  (ws + 3178752);
    unsigned long long* fkey = (unsigned long long*)(ws + 3309824);
    _Float16* ehi   = (_Float16*)(ws + 3571968);
    float* partial  = pd1;                       // pd1 dead after combine

    split_hi_kernel<<<dim3(BNR * DD / 2048), dim3(256), 0, stream>>>(z, xhi, 2048.0f, counters);
    split_hi_kernel<<<dim3(KC * DD / 2048), dim3(256), 0, stream>>>(embed, ehi, 1048576.0f, nullptr);
    rowsq_wave_kernel<<<dim3(BNR / 4), dim3(256), 0, stream>>>(z, a32, BNR);
    rowsq_wave_kernel<<<dim3(KC / 4), dim3(256), 0, stream>>>(embed, ce, KC);
    mfma_argmin_kernel<<<dim3((BNR / 128) * NQ), dim3(256), 0, stream>>>(
        xhi, ehi, ce, pd1, pi1, pd2, pi2, pd3);
    combine_kernel<<<dim3(BNR / 256), dim3(256), 0, stream>>>(
        pd1, pi1, pd2, pi2, pd3, a32, codes, pairlist, fulllist, fkey, counters);
    pair_repair_kernel<<<dim3(8192), dim3(256), 0, stream>>>(
        z, embed, ce, a32, pairlist, counters, codes);
    full_repair_kernel<<<dim3(16384), dim3(256), 0, stream>>>(
        z, embed, ce, a32, fulllist, counters, fkey);
    full_combine_kernel<<<dim3(128), dim3(256), 0, stream>>>(
        fkey, fulllist, counters, codes);
    gather_loss_kernel<<<dim3(BNR), dim3(128), 0, stream>>>(
        z, embed, codes, out_zq, out_codes, partial);
    loss_reduce_kernel<<<dim3(1), dim3(256), 0, stream>>>(partial, out_loss);
}